// Round 7
// baseline (233.780 us; speedup 1.0000x reference)
//
#include <hip/hip_runtime.h>

// RegLoss: l1(masked preds, targets) + 0.1 * mse(masked edge directions)
// preds, targets: [128, 1024, 151] fp32. Output: 1 fp32 scalar.
//
// Identities:
//   targets * (targets != 0) == targets       (masking targets is identity)
//   (m*pd - m*td)^2 == m*(pd - td)^2          (m in {0,1})
//   diff/(len+tiny) == (d2 > 0 ? diff*rsq(d2) : 0)  (~1e-7 rel; thresh 2.4e-2)
//
// R7 = R4's best-known structure (62.3 us: wave-autonomous, premasked
// interleaved {pm,tm} LDS layout, b64 gathers, v_rsq) + single-dispatch
// finish: each block adds ONE pre-scaled contribution to d_out[0] via
// native f32 global atomic (agent scope). No finalize kernel, no ws.
// R3-R6 established the ~63 us kernel floor is external (all pipes <35%,
// fully-cached replays equally slow); this round removes the last
// structural overhead (2nd dispatch + gap).

#define N_ROWS   (128 * 1024)
#define ROW      151
#define N_EDGES  47
#define GRID     8192
#define BLOCK    256
#define ROWS_PER_WAVE 4                     // GRID * 4 waves * 4 rows = N_ROWS
#define WAVE_DWORDS (ROWS_PER_WAVE * ROW)   // 604 (divisible by 4 -> 16B tiles)
#define WAVE_F4 (WAVE_DWORDS / 4)           // 151 float4 per array per wave
#define WAVE_TASKS (ROWS_PER_WAVE * N_EDGES) // 188
#define S_STRIDE (ROW * 2)                  // interleaved row stride (dwords)

// pre-scaled loss coefficients (mean denominators folded in)
#define C_L1  ((float)(1.0 / ((double)N_ROWS * 151.0)))
#define C_VEL ((float)(0.1 / ((double)N_ROWS * 141.0)))

#if __has_builtin(__builtin_amdgcn_rsqf)
__device__ __forceinline__ float fast_rsq(float x) { return __builtin_amdgcn_rsqf(x); }
#else
__device__ __forceinline__ float fast_rsq(float x) {
    float r; asm volatile("v_rsq_f32 %0, %1" : "=v"(r) : "v"(x)); return r;
}
#endif

// packed: low16 = parent*6 (interleaved dword offset), high16 = child*6
#define E(p, c) ((unsigned)((p) * 6) | ((unsigned)((c) * 6) << 16))
__constant__ unsigned c_edge[N_EDGES] = {
    E(0,1),  E(1,2),  E(2,3),  E(3,29), E(1,5),  E(5,6),  E(6,8),  E(8,9),
    E(8,13), E(8,17), E(8,21), E(8,25), E(9,10), E(10,11),E(11,12),E(13,14),
    E(14,15),E(15,16),E(17,18),E(18,19),E(19,20),E(21,22),E(22,23),E(23,24),
    E(25,26),E(26,27),E(27,28),E(29,30),E(29,34),E(29,38),E(29,42),E(29,46),
    E(30,31),E(31,32),E(32,33),E(34,35),E(35,36),E(36,37),E(38,39),E(39,40),
    E(40,41),E(42,43),E(43,44),E(44,45),E(46,47),E(47,48),E(48,49)};

__global__ __launch_bounds__(BLOCK) void reg_loss_main(
        const float* __restrict__ preds, const float* __restrict__ targets,
        float* __restrict__ out) {
    __shared__ float S[4][ROWS_PER_WAVE * S_STRIDE];   // per-wave slice, 4832 B
    __shared__ float redC[4];

    const int t = threadIdx.x;
    const int lane = t & 63;
    const int wave = t >> 6;
    float* __restrict__ Sw = S[wave];
    float4* __restrict__ S4 = (float4*)Sw;

    const long long base = ((long long)blockIdx.x * 4 + wave) * WAVE_DWORDS;
    const float4* __restrict__ p4 = (const float4*)(preds + base);
    const float4* __restrict__ t4 = (const float4*)(targets + base);

    // ---- precompute phase-2 task descriptors (overlaps global latency) ----
    int tr[3], te[3], tpi[3], tci[3];
#pragma unroll
    for (int k = 0; k < 3; ++k) {
        int task = lane + k * 64;
        int r = task / N_EDGES;            // magic-mul
        int e = task - r * N_EDGES;
        if (task >= WAVE_TASKS) { r = 0; e = 0; }   // inert clamp
        tr[k] = r; te[k] = e;
        unsigned pk = c_edge[e];
        tpi[k] = pk & 0xffff;
        tci[k] = pk >> 16;
    }

    float l1 = 0.f;
    float vel = 0.f;

    // ---- phase 1: stage own 4 rows, interleaved {pm, tm}; compute l1 ----
#pragma unroll
    for (int k = 0; k < 3; ++k) {
        int i = lane + k * 64;
        if (i < WAVE_F4) {
            float4 pv = p4[i];
            float4 tv = t4[i];
            float4 pm;
            pm.x = (tv.x != 0.f) ? pv.x : 0.f;
            pm.y = (tv.y != 0.f) ? pv.y : 0.f;
            pm.z = (tv.z != 0.f) ? pv.z : 0.f;
            pm.w = (tv.w != 0.f) ? pv.w : 0.f;
            l1 += fabsf(pm.x - tv.x) + fabsf(pm.y - tv.y)
                + fabsf(pm.z - tv.z) + fabsf(pm.w - tv.w);
            float4 a = {pm.x, tv.x, pm.y, tv.y};
            float4 b = {pm.z, tv.z, pm.w, tv.w};
            S4[i * 2]     = a;     // ds_write_b128, lanes consecutive 32B
            S4[i * 2 + 1] = b;
        }
    }
    // no __syncthreads: wave reads only its own slice (lgkmcnt handles RAW)

    // ---- phase 2: 188 edge tasks over 64 lanes ----
#pragma unroll
    for (int k = 0; k < 3; ++k) {
        int task = lane + k * 64;
        if (task < WAVE_TASKS) {
            const float* __restrict__ R = Sw + tr[k] * S_STRIDE;
            int pi = tpi[k], ci = tci[k], e = te[k];
            float2 px = *(const float2*)(R + pi);
            float2 py = *(const float2*)(R + pi + 2);
            float2 pz = *(const float2*)(R + pi + 4);
            float2 cx = *(const float2*)(R + ci);
            float2 cy = *(const float2*)(R + ci + 2);
            float2 cz = *(const float2*)(R + ci + 4);
            float pdx = px.x - cx.x, pdy = py.x - cy.x, pdz = pz.x - cz.x;
            float tdx = px.y - cx.y, tdy = py.y - cy.y, tdz = pz.y - cz.y;
            float pd2 = pdx * pdx + pdy * pdy + pdz * pdz;
            float td2 = tdx * tdx + tdy * tdy + tdz * tdz;
            float pinv = (pd2 > 0.f) ? fast_rsq(pd2) : 0.f;
            float tinv = (td2 > 0.f) ? fast_rsq(td2) : 0.f;
            float dx = pdx * pinv - tdx * tinv;
            float dy = pdy * pinv - tdy * tinv;
            float dz = pdz * pinv - tdz * tinv;
            float m0 = (R[e * 2 + 1]        != 0.f) ? 1.f : 0.f;
            float m1 = (R[(47 + e) * 2 + 1] != 0.f) ? 1.f : 0.f;
            float m2 = (R[(94 + e) * 2 + 1] != 0.f) ? 1.f : 0.f;
            vel += m0 * dx * dx + m1 * dy * dy + m2 * dz * dz;
        }
    }

    // ---- block reduction -> one pre-scaled atomic per block ----
    float c = l1 * C_L1 + vel * C_VEL;
#pragma unroll
    for (int off = 32; off > 0; off >>= 1) {
        c += __shfl_down(c, off);
    }
    if (lane == 0) { redC[wave] = c; }
    __syncthreads();
    if (t == 0) {
        float blockC = redC[0] + redC[1] + redC[2] + redC[3];
        // native f32 global atomic (agent scope) -> d_out[0]
        __hip_atomic_fetch_add(out, blockC, __ATOMIC_RELAXED,
                               __HIP_MEMORY_SCOPE_AGENT);
    }
}

extern "C" void kernel_launch(void* const* d_in, const int* in_sizes, int n_in,
                              void* d_out, int out_size, void* d_ws, size_t ws_size,
                              hipStream_t stream) {
    const float* preds   = (const float*)d_in[0];
    const float* targets = (const float*)d_in[1];
    float* out = (float*)d_out;

    hipMemsetAsync(d_out, 0, sizeof(float), stream);   // accumulator := 0
    reg_loss_main<<<GRID, BLOCK, 0, stream>>>(preds, targets, out);
}

// Round 8
// 185.783 us; speedup vs baseline: 1.2583x; 1.2583x over previous
//
#include <hip/hip_runtime.h>

// RegLoss: l1(masked preds, targets) + 0.1 * mse(masked edge directions)
// preds, targets: [128, 1024, 151] fp32. Output: 1 fp32 scalar.
//
// Identities:
//   targets * (targets != 0) == targets       (masking targets is identity)
//   (m*pd - m*td)^2 == m*(pd - td)^2          (m in {0,1})
//   diff/(len+tiny) == (d2 > 0 ? diff*rsq(d2) : 0)  (~1e-7 rel; thresh 2.4e-2)
//
// R8 = R4's body (best known: premasked interleaved {pm,tm} LDS, b64
// gathers, v_rsq) made persistent: GRID=2048, each wave loops 4 contiguous
// chunks of 4 rows synchronously. LDS 19.4KB/block -> exactly 8 blocks/CU
// (32 waves/CU, declared via __launch_bounds__(256,8)); 4x longer waves
// amortize ramp/drain; 8 blocks' load bursts interleave per CU.
// R7's single-address f32 atomic serialized (14 ns/RMW x 8192 = +54 us);
// reverted to ws partials + finalize kernel (measured ~6 us of dur).

#define N_ROWS   (128 * 1024)
#define ROW      151
#define N_EDGES  47
#define GRID     2048
#define BLOCK    256
#define CHUNKS   4                      // 2048 blk * 4 waves * 4 chunks * 4 rows
#define CHUNK_ROWS 4
#define CHUNK_DW (CHUNK_ROWS * ROW)     // 604 (div by 4 -> 16B-aligned chunks)
#define CHUNK_F4 (CHUNK_DW / 4)         // 151 float4 per array per chunk
#define CHUNK_TASKS (CHUNK_ROWS * N_EDGES) // 188
#define S_STRIDE (ROW * 2)              // interleaved row stride (dwords)

#if __has_builtin(__builtin_amdgcn_rsqf)
__device__ __forceinline__ float fast_rsq(float x) { return __builtin_amdgcn_rsqf(x); }
#else
__device__ __forceinline__ float fast_rsq(float x) {
    float r; asm volatile("v_rsq_f32 %0, %1" : "=v"(r) : "v"(x)); return r;
}
#endif

// packed: low16 = parent*6 (interleaved dword offset), high16 = child*6
#define E(p, c) ((unsigned)((p) * 6) | ((unsigned)((c) * 6) << 16))
__constant__ unsigned c_edge[N_EDGES] = {
    E(0,1),  E(1,2),  E(2,3),  E(3,29), E(1,5),  E(5,6),  E(6,8),  E(8,9),
    E(8,13), E(8,17), E(8,21), E(8,25), E(9,10), E(10,11),E(11,12),E(13,14),
    E(14,15),E(15,16),E(17,18),E(18,19),E(19,20),E(21,22),E(22,23),E(23,24),
    E(25,26),E(26,27),E(27,28),E(29,30),E(29,34),E(29,38),E(29,42),E(29,46),
    E(30,31),E(31,32),E(32,33),E(34,35),E(35,36),E(36,37),E(38,39),E(39,40),
    E(40,41),E(42,43),E(43,44),E(44,45),E(46,47),E(47,48),E(48,49)};

__global__ __launch_bounds__(BLOCK, 8) void reg_loss_main(
        const float* __restrict__ preds, const float* __restrict__ targets,
        float* __restrict__ wsL, float* __restrict__ wsV) {
    __shared__ float S[4][CHUNK_ROWS * S_STRIDE];   // per-wave slice, 4832 B
    __shared__ float redL[4], redV[4];

    const int t = threadIdx.x;
    const int lane = t & 63;
    const int wave = t >> 6;
    float* __restrict__ Sw = S[wave];
    float4* __restrict__ S4 = (float4*)Sw;

    const long long wb =
        (long long)(blockIdx.x * 4 + wave) * (CHUNKS * CHUNK_DW);
    const float4* __restrict__ p4 = (const float4*)(preds + wb);
    const float4* __restrict__ t4 = (const float4*)(targets + wb);

    // ---- per-lane phase-2 task descriptors (fixed across chunks) ----
    int tr[3], te[3], tpi[3], tci[3];
    bool tact[3];
#pragma unroll
    for (int k = 0; k < 3; ++k) {
        int task = lane + k * 64;
        tact[k] = task < CHUNK_TASKS;
        int r = task / N_EDGES;            // magic-mul
        int e = task - r * N_EDGES;
        if (!tact[k]) { r = 0; e = 0; }
        tr[k] = r * S_STRIDE; te[k] = e;
        unsigned pk = c_edge[e];
        tpi[k] = pk & 0xffff;
        tci[k] = pk >> 16;
    }

    float l1 = 0.f;
    float vel = 0.f;

    for (int c = 0; c < CHUNKS; ++c) {
        const float4* __restrict__ cp4 = p4 + c * CHUNK_F4;
        const float4* __restrict__ ct4 = t4 + c * CHUNK_F4;

        // ---- phase 1: stage 4 rows, interleaved {pm, tm}; compute l1 ----
#pragma unroll
        for (int k = 0; k < 3; ++k) {
            int i = lane + k * 64;
            if (i < CHUNK_F4) {
                float4 pv = cp4[i];
                float4 tv = ct4[i];
                float4 pm;
                pm.x = (tv.x != 0.f) ? pv.x : 0.f;
                pm.y = (tv.y != 0.f) ? pv.y : 0.f;
                pm.z = (tv.z != 0.f) ? pv.z : 0.f;
                pm.w = (tv.w != 0.f) ? pv.w : 0.f;
                l1 += fabsf(pm.x - tv.x) + fabsf(pm.y - tv.y)
                    + fabsf(pm.z - tv.z) + fabsf(pm.w - tv.w);
                float4 a = {pm.x, tv.x, pm.y, tv.y};
                float4 b = {pm.z, tv.z, pm.w, tv.w};
                S4[i * 2]     = a;     // ds_write_b128, lanes consecutive 32B
                S4[i * 2 + 1] = b;
            }
        }
        // no __syncthreads: wave reads only its own slice (lgkmcnt orders RAW)

        // ---- phase 2: 188 edge tasks over 64 lanes ----
#pragma unroll
        for (int k = 0; k < 3; ++k) {
            if (tact[k]) {
                const float* __restrict__ R = Sw + tr[k];
                int pi = tpi[k], ci = tci[k], e = te[k];
                float2 px = *(const float2*)(R + pi);
                float2 py = *(const float2*)(R + pi + 2);
                float2 pz = *(const float2*)(R + pi + 4);
                float2 cx = *(const float2*)(R + ci);
                float2 cy = *(const float2*)(R + ci + 2);
                float2 cz = *(const float2*)(R + ci + 4);
                float pdx = px.x - cx.x, pdy = py.x - cy.x, pdz = pz.x - cz.x;
                float tdx = px.y - cx.y, tdy = py.y - cy.y, tdz = pz.y - cz.y;
                float pd2 = pdx * pdx + pdy * pdy + pdz * pdz;
                float td2 = tdx * tdx + tdy * tdy + tdz * tdz;
                float pinv = (pd2 > 0.f) ? fast_rsq(pd2) : 0.f;
                float tinv = (td2 > 0.f) ? fast_rsq(td2) : 0.f;
                float dx = pdx * pinv - tdx * tinv;
                float dy = pdy * pinv - tdy * tinv;
                float dz = pdz * pinv - tdz * tinv;
                float m0 = (R[e * 2 + 1]        != 0.f) ? 1.f : 0.f;
                float m1 = (R[(47 + e) * 2 + 1] != 0.f) ? 1.f : 0.f;
                float m2 = (R[(94 + e) * 2 + 1] != 0.f) ? 1.f : 0.f;
                vel += m0 * dx * dx + m1 * dy * dy + m2 * dz * dz;
            }
        }
        // next chunk overwrites Sw only after this wave's reads retired
        // (in-order DS pipe per wave; compiler inserts lgkmcnt waits)
    }

    // ---- block reduction -> per-block partials ----
#pragma unroll
    for (int off = 32; off > 0; off >>= 1) {
        l1  += __shfl_down(l1, off);
        vel += __shfl_down(vel, off);
    }
    if (lane == 0) { redL[wave] = l1; redV[wave] = vel; }
    __syncthreads();
    if (t == 0) {
        wsL[blockIdx.x] = redL[0] + redL[1] + redL[2] + redL[3];
        wsV[blockIdx.x] = redV[0] + redV[1] + redV[2] + redV[3];
    }
}

__global__ __launch_bounds__(BLOCK) void reg_loss_finalize(
        const float* __restrict__ wsL, const float* __restrict__ wsV,
        float* __restrict__ out) {
    __shared__ double rl[4], rv[4];
    const int t = threadIdx.x;
    const int lane = t & 63;
    const int wave = t >> 6;
    double L = 0.0, V = 0.0;
    for (int k = t; k < GRID; k += BLOCK) { L += wsL[k]; V += wsV[k]; }
#pragma unroll
    for (int off = 32; off > 0; off >>= 1) {
        L += __shfl_down(L, off);
        V += __shfl_down(V, off);
    }
    if (lane == 0) { rl[wave] = L; rv[wave] = V; }
    __syncthreads();
    if (t == 0) {
        double Ls = rl[0] + rl[1] + rl[2] + rl[3];
        double Vs = rv[0] + rv[1] + rv[2] + rv[3];
        out[0] = (float)(Ls / ((double)N_ROWS * 151.0)
                       + 0.1 * (Vs / ((double)N_ROWS * 141.0)));
    }
}

extern "C" void kernel_launch(void* const* d_in, const int* in_sizes, int n_in,
                              void* d_out, int out_size, void* d_ws, size_t ws_size,
                              hipStream_t stream) {
    const float* preds   = (const float*)d_in[0];
    const float* targets = (const float*)d_in[1];
    float* wsL = (float*)d_ws;
    float* wsV = wsL + GRID;
    float* out = (float*)d_out;

    reg_loss_main<<<GRID, BLOCK, 0, stream>>>(preds, targets, wsL, wsV);
    reg_loss_finalize<<<1, BLOCK, 0, stream>>>(wsL, wsV, out);
}